// Round 6
// baseline (96.714 us; speedup 1.0000x reference)
//
#include <hip/hip_runtime.h>
#include <math.h>

#define K1_NR 4    // k1 rows per strip (small => big grid => latency hiding)
#define SROWS 64   // pool rows per block strip
#define PCH   16   // pool rows per LDS phase
#define QCAP  1024 // k4 compaction queue entries

// ---------------- device helpers ----------------

__device__ __forceinline__ float srgb_to_linear(float x) {
    x = fminf(fmaxf(x, 0.0f), 1.0f);
    return (x <= 0.04045f) ? x * (1.0f / 12.92f)
                           : powf((x + 0.055f) * (1.0f / 1.055f), 2.4f);
}

__device__ __forceinline__ void oklab_ab(float r, float g, float b,
                                         float& A, float& Bc) {
    r = srgb_to_linear(r);
    g = srgb_to_linear(g);
    b = srgb_to_linear(b);
    float l = 0.4122214708f * r + 0.5363325363f * g + 0.0514459929f * b;
    float m = 0.2119034982f * r + 0.6806995451f * g + 0.1073969566f * b;
    float s = 0.0883024619f * r + 0.2817188376f * g + 0.6299787005f * b;
    l = cbrtf(fmaxf(l, 1e-10f));
    m = cbrtf(fmaxf(m, 1e-10f));
    s = cbrtf(fmaxf(s, 1e-10f));
    A  = 1.9779984951f * l - 2.428592205f * m + 0.4505937099f * s;
    Bc = 0.0259040371f * l + 0.7827717662f * m - 0.808675766f  * s;
}

__device__ __forceinline__ void color_terms(const float* __restrict__ pred,
                                            const float* __restrict__ target,
                                            size_t off, size_t HWp, float m,
                                            float& sc, float& sh) {
    float pa, pb, ta, tb;
    oklab_ab(pred[off], pred[off + HWp], pred[off + 2 * HWp], pa, pb);
    oklab_ab(target[off], target[off + HWp], target[off + 2 * HWp], ta, tb);
    float Cp = sqrtf(pa * pa + pb * pb + 1e-12f);
    float Cg = sqrtf(ta * ta + tb * tb + 1e-12f);
    sc += fabsf(Cp - Cg) * m;
    float cosd = (pa * ta + pb * tb) / (Cp * Cg + 1e-12f);
    cosd = fminf(fmaxf(cosd, -1.0f), 1.0f);
    sh += fmaxf(Cg, 0.01f) * (1.0f - cosd) * m;
}

// ---------------- K1: sobel edge_soft, float4 lanes ----------------
// Block = 4 waves; wave q covers cols [256q, 256q+256), lane covers 4 cols.
// Requires W == 1024. Wave-boundary neighbor cols via halo-lane scalar loads.
// K1_NR=4: grid = B*H/4 = 2048 blocks -> 8 blocks/CU (latency hiding).

__global__ __launch_bounds__(256) void k1_edge(const float* __restrict__ target,
                                               float* __restrict__ edge,
                                               int H, int W) {
    int strips = H / K1_NR;
    int b   = blockIdx.x / strips;
    int ysi = blockIdx.x % strips;
    int lane = threadIdx.x & 63, q = threadIdx.x >> 6;
    int C0 = q << 8;
    int col0 = C0 + (lane << 2);
    int y0 = ysi * K1_NR;
    size_t HW = (size_t)H * W;
    const float* tb = target + (size_t)b * 3 * HW;
    float* ep = edge + (size_t)b * HW;

    int hcol = (lane == 0) ? (C0 - 1) : (C0 + 256);
    bool hen = (lane == 0 || lane == 63) && (hcol >= 0) && (hcol < W);
    int lm = (lane + 63) & 63, lp = (lane + 1) & 63;

    float4 pr[3], cu[3], nx[3];
    float hpr[3], hcu[3], hnx[3];
#pragma unroll
    for (int c = 0; c < 3; ++c) {
        const float* p = tb + (size_t)c * HW;
        if (y0 > 0) {
            pr[c]  = *(const float4*)(p + (size_t)(y0 - 1) * W + col0);
            hpr[c] = hen ? p[(size_t)(y0 - 1) * W + hcol] : 0.f;
        } else {
            pr[c] = make_float4(0.f, 0.f, 0.f, 0.f);
            hpr[c] = 0.f;
        }
        cu[c]  = *(const float4*)(p + (size_t)y0 * W + col0);
        hcu[c] = hen ? p[(size_t)y0 * W + hcol] : 0.f;
    }

#pragma unroll
    for (int y = y0; y < y0 + K1_NR; ++y) {
        bool okn = (y + 1 < H);
#pragma unroll
        for (int c = 0; c < 3; ++c) {
            const float* p = tb + (size_t)c * HW + (size_t)(y + 1) * W;
            nx[c]  = okn ? *(const float4*)(p + col0)
                         : make_float4(0.f, 0.f, 0.f, 0.f);
            hnx[c] = (okn && hen) ? p[hcol] : 0.f;
        }
        float4 g = make_float4(0.f, 0.f, 0.f, 0.f);
#pragma unroll
        for (int c = 0; c < 3; ++c) {
            float4 u, v;
            u.x = fmaf(2.f, cu[c].x, pr[c].x) + nx[c].x;
            u.y = fmaf(2.f, cu[c].y, pr[c].y) + nx[c].y;
            u.z = fmaf(2.f, cu[c].z, pr[c].z) + nx[c].z;
            u.w = fmaf(2.f, cu[c].w, pr[c].w) + nx[c].w;
            v.x = nx[c].x - pr[c].x;
            v.y = nx[c].y - pr[c].y;
            v.z = nx[c].z - pr[c].z;
            v.w = nx[c].w - pr[c].w;
            float hu = fmaf(2.f, hcu[c], hpr[c]) + hnx[c];
            float hv = hnx[c] - hpr[c];
            float um1 = __shfl(u.w, lm); if (lane == 0)  um1 = hu;
            float up4 = __shfl(u.x, lp); if (lane == 63) up4 = hu;
            float vm1 = __shfl(v.w, lm); if (lane == 0)  vm1 = hv;
            float vp4 = __shfl(v.x, lp); if (lane == 63) vp4 = hv;
            float4 gx, gy;
            gx.x = u.y - um1; gx.y = u.z - u.x; gx.z = u.w - u.y; gx.w = up4 - u.z;
            gy.x = fmaf(2.f, v.x, vm1) + v.y;
            gy.y = fmaf(2.f, v.y, v.x) + v.z;
            gy.z = fmaf(2.f, v.z, v.y) + v.w;
            gy.w = fmaf(2.f, v.w, v.z) + vp4;
            g.x = fmaxf(g.x, fabsf(gx.x) + fabsf(gy.x));
            g.y = fmaxf(g.y, fabsf(gx.y) + fabsf(gy.y));
            g.z = fmaxf(g.z, fabsf(gx.z) + fabsf(gy.z));
            g.w = fmaxf(g.w, fabsf(gx.w) + fabsf(gy.w));
        }
        float4 e;
        e.x = fminf(2.f * g.x, 1.f);
        e.y = fminf(2.f * g.y, 1.f);
        e.z = fminf(2.f * g.z, 1.f);
        e.w = fminf(2.f * g.w, 1.f);
        *(float4*)(ep + (size_t)y * W + col0) = e;
#pragma unroll
        for (int c = 0; c < 3; ++c) {
            pr[c] = cu[c]; cu[c] = nx[c];
            hpr[c] = hcu[c]; hcu[c] = hnx[c];
        }
    }
}

// ---------------- column-strip 2-D pool (vertical in regs, horizontal via LDS) ----

template <int R, bool ISMAX, bool SUB_EDGE>
__global__ __launch_bounds__(256) void pool_kernel(const float* __restrict__ in,
                                                   const float* __restrict__ edge,
                                                   float* __restrict__ out,
                                                   int H, int W) {
    const int OUTW = 256 - 2 * R;
    __shared__ float s_v[PCH][256];
    int cb = (W + OUTW - 1) / OUTW;
    int rs = H / SROWS;
    int blk = blockIdx.x;
    int b   = blk / (cb * rs);
    int t   = blk % (cb * rs);
    int bxi = t / rs, ysi = t % rs;
    int tid = threadIdx.x;
    int col = bxi * OUTW - R + tid;
    int cc  = min(max(col, 0), W - 1);  // replicate == clamped window
    size_t base = (size_t)b * H * W;
    const float* colp = in + base + cc;
    int ys = ysi * SROWS;
    bool writer = (tid >= R) && (tid < OUTW + R) && (col < W);

    for (int ph = 0; ph < SROWS / PCH; ++ph) {
        int y0 = ys + ph * PCH;
        float w[PCH + 2 * R];
#pragma unroll
        for (int k = 0; k < PCH + 2 * R; ++k) {
            int r = min(max(y0 - R + k, 0), H - 1);
            w[k] = colp[(size_t)r * W];
        }
        float v[PCH];
#pragma unroll
        for (int k = 0; k < PCH; ++k) {
            float m = w[k];
#pragma unroll
            for (int d = 1; d <= 2 * R; ++d)
                m = ISMAX ? fmaxf(m, w[k + d]) : fminf(m, w[k + d]);
            v[k] = m;
        }
        __syncthreads();  // previous phase's readers done
#pragma unroll
        for (int k = 0; k < PCH; ++k) s_v[k][tid] = v[k];
        __syncthreads();
        if (writer) {
#pragma unroll
            for (int k = 0; k < PCH; ++k) {
                float m = s_v[k][tid - R];
#pragma unroll
                for (int d = 1; d <= 2 * R; ++d)
                    m = ISMAX ? fmaxf(m, s_v[k][tid - R + d])
                              : fminf(m, s_v[k][tid - R + d]);
                size_t gi = base + (size_t)(y0 + k) * W + col;
                out[gi] = SUB_EDGE ? fmaxf(m - edge[gi], 0.f) : m;
            }
        }
    }
}

// ---------------- K4: 5x5 max-pool + compacted masked OKLab loss ----------------

__global__ __launch_bounds__(256) void k4_loss(const float* __restrict__ pred,
                                               const float* __restrict__ target,
                                               const float* __restrict__ mask0,
                                               float* __restrict__ partials,
                                               int H, int W, int nb) {
    const int R = 2, OUTW = 256 - 2 * R;
    __shared__ float s_v[PCH][256];
    __shared__ int   q_pos[QCAP];
    __shared__ float q_m[QCAP];
    __shared__ int   cnt;
    __shared__ float s_red[3][4];

    int cb = (W + OUTW - 1) / OUTW;
    int rs = H / SROWS;
    int blk = blockIdx.x;
    int b   = blk / (cb * rs);
    int t   = blk % (cb * rs);
    int bxi = t / rs, ysi = t % rs;
    int tid = threadIdx.x;
    int col = bxi * OUTW - R + tid;
    int cc  = min(max(col, 0), W - 1);
    size_t HWp  = (size_t)H * W;
    size_t base = (size_t)b * HWp;
    size_t cbase = (size_t)b * 3 * HWp;
    const float* colp = mask0 + base + cc;
    int ys = ysi * SROWS;
    bool writer = (tid >= R) && (tid < OUTW + R) && (col < W);

    float sm = 0.f, sc = 0.f, sh = 0.f;

    for (int ph = 0; ph < SROWS / PCH; ++ph) {
        int y0 = ys + ph * PCH;
        float w[PCH + 2 * R];
#pragma unroll
        for (int k = 0; k < PCH + 2 * R; ++k) {
            int r = min(max(y0 - R + k, 0), H - 1);
            w[k] = colp[(size_t)r * W];
        }
        float v[PCH];
#pragma unroll
        for (int k = 0; k < PCH; ++k) {
            float m = w[k];
#pragma unroll
            for (int d = 1; d <= 2 * R; ++d) m = fmaxf(m, w[k + d]);
            v[k] = m;
        }
        __syncthreads();  // prev phase queue-processing done
#pragma unroll
        for (int k = 0; k < PCH; ++k) s_v[k][tid] = v[k];
        if (tid == 0) cnt = 0;
        __syncthreads();
        if (writer) {
#pragma unroll
            for (int k = 0; k < PCH; ++k) {
                float m = s_v[k][tid - R];
#pragma unroll
                for (int d = 1; d <= 2 * R; ++d)
                    m = fmaxf(m, s_v[k][tid - R + d]);
                sm += m;
                if (m > 0.f) {
                    int pos = atomicAdd(&cnt, 1);
                    if (pos < QCAP) {
                        q_pos[pos] = ((y0 + k) << 16) | col;
                        q_m[pos] = m;
                    } else {  // overflow fallback (dense mask) — compute inline
                        color_terms(pred, target,
                                    cbase + (size_t)(y0 + k) * W + col,
                                    HWp, m, sc, sh);
                    }
                }
            }
        }
        __syncthreads();
        int n = min(cnt, QCAP);
        for (int i = tid; i < n; i += 256) {
            int pk = q_pos[i];
            color_terms(pred, target,
                        cbase + (size_t)(pk >> 16) * W + (pk & 0xffff),
                        HWp, q_m[i], sc, sh);
        }
    }

    // wave reduce (64 lanes)
#pragma unroll
    for (int off = 32; off > 0; off >>= 1) {
        sm += __shfl_down(sm, off);
        sc += __shfl_down(sc, off);
        sh += __shfl_down(sh, off);
    }
    int lane = tid & 63, wav = tid >> 6;
    __syncthreads();
    if (lane == 0) { s_red[0][wav] = sm; s_red[1][wav] = sc; s_red[2][wav] = sh; }
    __syncthreads();
    if (tid == 0) {
        float tm = 0, tc = 0, th = 0;
        for (int i = 0; i < 4; ++i) {
            tm += s_red[0][i]; tc += s_red[1][i]; th += s_red[2][i];
        }
        partials[blk]          = tm;
        partials[nb + blk]     = tc;
        partials[2 * nb + blk] = th;
    }
}

__global__ void finalize_kernel(const float* __restrict__ partials, int nb,
                                float* __restrict__ out) {
    double sm = 0.0, sc = 0.0, sh = 0.0;
    for (int i = threadIdx.x; i < nb; i += blockDim.x) {
        sm += (double)partials[i];
        sc += (double)partials[nb + i];
        sh += (double)partials[2 * nb + i];
    }
    __shared__ double red[3][256];
    red[0][threadIdx.x] = sm;
    red[1][threadIdx.x] = sc;
    red[2][threadIdx.x] = sh;
    __syncthreads();
    for (int s = blockDim.x / 2; s > 0; s >>= 1) {
        if ((int)threadIdx.x < s) {
            red[0][threadIdx.x] += red[0][threadIdx.x + s];
            red[1][threadIdx.x] += red[1][threadIdx.x + s];
            red[2][threadIdx.x] += red[2][threadIdx.x + s];
        }
        __syncthreads();
    }
    if (threadIdx.x == 0) {
        double ms = fmax(red[0][0], 1.0);
        out[0] = (float)(red[1][0] / ms + 2.0 * red[2][0] / ms);
    }
}

// ---------------- host launch ----------------

extern "C" void kernel_launch(void* const* d_in, const int* in_sizes, int n_in,
                              void* d_out, int out_size, void* d_ws, size_t ws_size,
                              hipStream_t stream) {
    const float* pred   = (const float*)d_in[0];
    const float* target = (const float*)d_in[1];
    float* out = (float*)d_out;

    const int H = 1024, W = 1024;  // fixed problem shape (W==1024 required by k1)
    int Bn = in_sizes[0] / (3 * H * W);
    size_t plane = (size_t)Bn * H * W * sizeof(float);

    char* ws = (char*)d_ws;
    float* planeA = (float*)ws;            // edge, then mask0 (in place)
    float* planeB = (float*)(ws + plane);  // dilated
    float* partials = (float*)(ws + 2 * plane);

    int g1 = Bn * (H / K1_NR);                 // 2048
    int rs = H / SROWS;                        // 16
    int cbP = (W + 245) / 246;                 // 5
    int cb4 = (W + 251) / 252;                 // 5
    int gP = Bn * cbP * rs;
    int g4 = Bn * cb4 * rs;

    // 1. sobel edge_soft -> planeA
    k1_edge<<<g1, 256, 0, stream>>>(target, planeA, H, W);
    // 2. 11x11 max-pool -> planeB (dilated)
    pool_kernel<5, true, false><<<gP, 256, 0, stream>>>(planeA, nullptr, planeB, H, W);
    // 3. 11x11 min-pool + relu(closed - edge) -> planeA in place (mask0)
    pool_kernel<5, false, true><<<gP, 256, 0, stream>>>(planeB, planeA, planeA, H, W);
    // 4. 5x5 max-pool + compacted masked loss -> partials
    k4_loss<<<g4, 256, 0, stream>>>(pred, target, planeA, partials, H, W, g4);
    // 5. final reduce + combine
    finalize_kernel<<<1, 256, 0, stream>>>(partials, g4, out);
}

// Round 7
// 92.734 us; speedup vs baseline: 1.0429x; 1.0429x over previous
//
#include <hip/hip_runtime.h>
#include <math.h>

#define K1_NR 8    // k1 rows per strip (grid = B*H/8 = 1024 blocks)
#define SROWS 64   // pool rows per block strip
#define PCH   16   // pool rows per LDS phase
#define QCAP  1024 // k4 compaction queue entries

// ---------------- device helpers ----------------

__device__ __forceinline__ float srgb_to_linear(float x) {
    x = fminf(fmaxf(x, 0.0f), 1.0f);
    return (x <= 0.04045f) ? x * (1.0f / 12.92f)
                           : powf((x + 0.055f) * (1.0f / 1.055f), 2.4f);
}

__device__ __forceinline__ void oklab_ab(float r, float g, float b,
                                         float& A, float& Bc) {
    r = srgb_to_linear(r);
    g = srgb_to_linear(g);
    b = srgb_to_linear(b);
    float l = 0.4122214708f * r + 0.5363325363f * g + 0.0514459929f * b;
    float m = 0.2119034982f * r + 0.6806995451f * g + 0.1073969566f * b;
    float s = 0.0883024619f * r + 0.2817188376f * g + 0.6299787005f * b;
    l = cbrtf(fmaxf(l, 1e-10f));
    m = cbrtf(fmaxf(m, 1e-10f));
    s = cbrtf(fmaxf(s, 1e-10f));
    A  = 1.9779984951f * l - 2.428592205f * m + 0.4505937099f * s;
    Bc = 0.0259040371f * l + 0.7827717662f * m - 0.808675766f  * s;
}

__device__ __forceinline__ void color_terms(const float* __restrict__ pred,
                                            const float* __restrict__ target,
                                            size_t off, size_t HWp, float m,
                                            float& sc, float& sh) {
    float pa, pb, ta, tb;
    oklab_ab(pred[off], pred[off + HWp], pred[off + 2 * HWp], pa, pb);
    oklab_ab(target[off], target[off + HWp], target[off + 2 * HWp], ta, tb);
    float Cp = sqrtf(pa * pa + pb * pb + 1e-12f);
    float Cg = sqrtf(ta * ta + tb * tb + 1e-12f);
    sc += fabsf(Cp - Cg) * m;
    float cosd = (pa * ta + pb * tb) / (Cp * Cg + 1e-12f);
    cosd = fminf(fmaxf(cosd, -1.0f), 1.0f);
    sh += fmaxf(Cg, 0.01f) * (1.0f - cosd) * m;
}

// ---------------- K1: sobel edge_soft, float4 lanes, ZERO shuffles ----------
// Horizontal halo (col0-1, col0+4) loaded directly as scalars — neighbor
// lanes own those cache lines, so these are L1 hits. No DS-pipe traffic.
// Requires W == 1024 (block of 4 waves spans the full row).

__global__ __launch_bounds__(256) void k1_edge(const float* __restrict__ target,
                                               float* __restrict__ edge,
                                               int H, int W) {
    int strips = H / K1_NR;
    int b   = blockIdx.x / strips;
    int ysi = blockIdx.x % strips;
    int lane = threadIdx.x & 63, q = threadIdx.x >> 6;
    int col0 = (q << 8) + (lane << 2);
    int y0 = ysi * K1_NR;
    size_t HW = (size_t)H * W;
    const float* tb = target + (size_t)b * 3 * HW;
    float* ep = edge + (size_t)b * HW + col0;

    bool lok = (col0 > 0);          // image-left zero-pad only at x==0
    bool rok = (col0 + 4 < W);      // image-right zero-pad only at x==W-1
    int lc = lok ? col0 - 1 : 0;
    int rc = rok ? col0 + 4 : W - 1;

    float4 pr[3], cu[3], nx[3];
    float lpr[3], lcu[3], lnx[3], rpr[3], rcu[3], rnx[3];
#pragma unroll
    for (int c = 0; c < 3; ++c) {
        const float* p = tb + (size_t)c * HW;
        if (y0 > 0) {
            const float* r = p + (size_t)(y0 - 1) * W;
            pr[c]  = *(const float4*)(r + col0);
            lpr[c] = lok ? r[lc] : 0.f;
            rpr[c] = rok ? r[rc] : 0.f;
        } else {
            pr[c] = make_float4(0.f, 0.f, 0.f, 0.f);
            lpr[c] = 0.f; rpr[c] = 0.f;
        }
        const float* r = p + (size_t)y0 * W;
        cu[c]  = *(const float4*)(r + col0);
        lcu[c] = lok ? r[lc] : 0.f;
        rcu[c] = rok ? r[rc] : 0.f;
    }

#pragma unroll
    for (int y = y0; y < y0 + K1_NR; ++y) {
        bool okn = (y + 1 < H);
#pragma unroll
        for (int c = 0; c < 3; ++c) {
            const float* r = tb + (size_t)c * HW + (size_t)(y + 1) * W;
            nx[c]  = okn ? *(const float4*)(r + col0)
                         : make_float4(0.f, 0.f, 0.f, 0.f);
            lnx[c] = (okn && lok) ? r[lc] : 0.f;
            rnx[c] = (okn && rok) ? r[rc] : 0.f;
        }
        float4 g = make_float4(0.f, 0.f, 0.f, 0.f);
#pragma unroll
        for (int c = 0; c < 3; ++c) {
            float4 u, v;
            u.x = fmaf(2.f, cu[c].x, pr[c].x) + nx[c].x;
            u.y = fmaf(2.f, cu[c].y, pr[c].y) + nx[c].y;
            u.z = fmaf(2.f, cu[c].z, pr[c].z) + nx[c].z;
            u.w = fmaf(2.f, cu[c].w, pr[c].w) + nx[c].w;
            v.x = nx[c].x - pr[c].x;
            v.y = nx[c].y - pr[c].y;
            v.z = nx[c].z - pr[c].z;
            v.w = nx[c].w - pr[c].w;
            float ul = fmaf(2.f, lcu[c], lpr[c]) + lnx[c];
            float vl = lnx[c] - lpr[c];
            float ur = fmaf(2.f, rcu[c], rpr[c]) + rnx[c];
            float vr = rnx[c] - rpr[c];
            float4 gx, gy;
            gx.x = u.y - ul;  gx.y = u.z - u.x;
            gx.z = u.w - u.y; gx.w = ur - u.z;
            gy.x = fmaf(2.f, v.x, vl)  + v.y;
            gy.y = fmaf(2.f, v.y, v.x) + v.z;
            gy.z = fmaf(2.f, v.z, v.y) + v.w;
            gy.w = fmaf(2.f, v.w, v.z) + vr;
            g.x = fmaxf(g.x, fabsf(gx.x) + fabsf(gy.x));
            g.y = fmaxf(g.y, fabsf(gx.y) + fabsf(gy.y));
            g.z = fmaxf(g.z, fabsf(gx.z) + fabsf(gy.z));
            g.w = fmaxf(g.w, fabsf(gx.w) + fabsf(gy.w));
        }
        float4 e;
        e.x = fminf(2.f * g.x, 1.f);
        e.y = fminf(2.f * g.y, 1.f);
        e.z = fminf(2.f * g.z, 1.f);
        e.w = fminf(2.f * g.w, 1.f);
        *(float4*)(ep + (size_t)y * W) = e;
#pragma unroll
        for (int c = 0; c < 3; ++c) {
            pr[c] = cu[c];   cu[c] = nx[c];
            lpr[c] = lcu[c]; lcu[c] = lnx[c];
            rpr[c] = rcu[c]; rcu[c] = rnx[c];
        }
    }
}

// ---------------- column-strip 2-D pool (vertical in regs, horizontal via LDS) ----

template <int R, bool ISMAX, bool SUB_EDGE>
__global__ __launch_bounds__(256) void pool_kernel(const float* __restrict__ in,
                                                   const float* __restrict__ edge,
                                                   float* __restrict__ out,
                                                   int H, int W) {
    const int OUTW = 256 - 2 * R;
    __shared__ float s_v[PCH][256];
    int cb = (W + OUTW - 1) / OUTW;
    int rs = H / SROWS;
    int blk = blockIdx.x;
    int b   = blk / (cb * rs);
    int t   = blk % (cb * rs);
    int bxi = t / rs, ysi = t % rs;
    int tid = threadIdx.x;
    int col = bxi * OUTW - R + tid;
    int cc  = min(max(col, 0), W - 1);  // replicate == clamped window
    size_t base = (size_t)b * H * W;
    const float* colp = in + base + cc;
    int ys = ysi * SROWS;
    bool writer = (tid >= R) && (tid < OUTW + R) && (col < W);

    for (int ph = 0; ph < SROWS / PCH; ++ph) {
        int y0 = ys + ph * PCH;
        float w[PCH + 2 * R];
#pragma unroll
        for (int k = 0; k < PCH + 2 * R; ++k) {
            int r = min(max(y0 - R + k, 0), H - 1);
            w[k] = colp[(size_t)r * W];
        }
        float v[PCH];
#pragma unroll
        for (int k = 0; k < PCH; ++k) {
            float m = w[k];
#pragma unroll
            for (int d = 1; d <= 2 * R; ++d)
                m = ISMAX ? fmaxf(m, w[k + d]) : fminf(m, w[k + d]);
            v[k] = m;
        }
        __syncthreads();  // previous phase's readers done
#pragma unroll
        for (int k = 0; k < PCH; ++k) s_v[k][tid] = v[k];
        __syncthreads();
        if (writer) {
#pragma unroll
            for (int k = 0; k < PCH; ++k) {
                float m = s_v[k][tid - R];
#pragma unroll
                for (int d = 1; d <= 2 * R; ++d)
                    m = ISMAX ? fmaxf(m, s_v[k][tid - R + d])
                              : fminf(m, s_v[k][tid - R + d]);
                size_t gi = base + (size_t)(y0 + k) * W + col;
                out[gi] = SUB_EDGE ? fmaxf(m - edge[gi], 0.f) : m;
            }
        }
    }
}

// ---------------- K4: 5x5 max-pool + compacted masked OKLab loss ----------------

__global__ __launch_bounds__(256) void k4_loss(const float* __restrict__ pred,
                                               const float* __restrict__ target,
                                               const float* __restrict__ mask0,
                                               float* __restrict__ partials,
                                               int H, int W, int nb) {
    const int R = 2, OUTW = 256 - 2 * R;
    __shared__ float s_v[PCH][256];
    __shared__ int   q_pos[QCAP];
    __shared__ float q_m[QCAP];
    __shared__ int   cnt;
    __shared__ float s_red[3][4];

    int cb = (W + OUTW - 1) / OUTW;
    int rs = H / SROWS;
    int blk = blockIdx.x;
    int b   = blk / (cb * rs);
    int t   = blk % (cb * rs);
    int bxi = t / rs, ysi = t % rs;
    int tid = threadIdx.x;
    int col = bxi * OUTW - R + tid;
    int cc  = min(max(col, 0), W - 1);
    size_t HWp  = (size_t)H * W;
    size_t base = (size_t)b * HWp;
    size_t cbase = (size_t)b * 3 * HWp;
    const float* colp = mask0 + base + cc;
    int ys = ysi * SROWS;
    bool writer = (tid >= R) && (tid < OUTW + R) && (col < W);

    float sm = 0.f, sc = 0.f, sh = 0.f;

    for (int ph = 0; ph < SROWS / PCH; ++ph) {
        int y0 = ys + ph * PCH;
        float w[PCH + 2 * R];
#pragma unroll
        for (int k = 0; k < PCH + 2 * R; ++k) {
            int r = min(max(y0 - R + k, 0), H - 1);
            w[k] = colp[(size_t)r * W];
        }
        float v[PCH];
#pragma unroll
        for (int k = 0; k < PCH; ++k) {
            float m = w[k];
#pragma unroll
            for (int d = 1; d <= 2 * R; ++d) m = fmaxf(m, w[k + d]);
            v[k] = m;
        }
        __syncthreads();  // prev phase queue-processing done
#pragma unroll
        for (int k = 0; k < PCH; ++k) s_v[k][tid] = v[k];
        if (tid == 0) cnt = 0;
        __syncthreads();
        if (writer) {
#pragma unroll
            for (int k = 0; k < PCH; ++k) {
                float m = s_v[k][tid - R];
#pragma unroll
                for (int d = 1; d <= 2 * R; ++d)
                    m = fmaxf(m, s_v[k][tid - R + d]);
                sm += m;
                if (m > 0.f) {
                    int pos = atomicAdd(&cnt, 1);
                    if (pos < QCAP) {
                        q_pos[pos] = ((y0 + k) << 16) | col;
                        q_m[pos] = m;
                    } else {  // overflow fallback (dense mask) — compute inline
                        color_terms(pred, target,
                                    cbase + (size_t)(y0 + k) * W + col,
                                    HWp, m, sc, sh);
                    }
                }
            }
        }
        __syncthreads();
        int n = min(cnt, QCAP);
        for (int i = tid; i < n; i += 256) {
            int pk = q_pos[i];
            color_terms(pred, target,
                        cbase + (size_t)(pk >> 16) * W + (pk & 0xffff),
                        HWp, q_m[i], sc, sh);
        }
    }

    // wave reduce (64 lanes)
#pragma unroll
    for (int off = 32; off > 0; off >>= 1) {
        sm += __shfl_down(sm, off);
        sc += __shfl_down(sc, off);
        sh += __shfl_down(sh, off);
    }
    int lane = tid & 63, wav = tid >> 6;
    __syncthreads();
    if (lane == 0) { s_red[0][wav] = sm; s_red[1][wav] = sc; s_red[2][wav] = sh; }
    __syncthreads();
    if (tid == 0) {
        float tm = 0, tc = 0, th = 0;
        for (int i = 0; i < 4; ++i) {
            tm += s_red[0][i]; tc += s_red[1][i]; th += s_red[2][i];
        }
        partials[blk]          = tm;
        partials[nb + blk]     = tc;
        partials[2 * nb + blk] = th;
    }
}

__global__ void finalize_kernel(const float* __restrict__ partials, int nb,
                                float* __restrict__ out) {
    double sm = 0.0, sc = 0.0, sh = 0.0;
    for (int i = threadIdx.x; i < nb; i += blockDim.x) {
        sm += (double)partials[i];
        sc += (double)partials[nb + i];
        sh += (double)partials[2 * nb + i];
    }
    __shared__ double red[3][256];
    red[0][threadIdx.x] = sm;
    red[1][threadIdx.x] = sc;
    red[2][threadIdx.x] = sh;
    __syncthreads();
    for (int s = blockDim.x / 2; s > 0; s >>= 1) {
        if ((int)threadIdx.x < s) {
            red[0][threadIdx.x] += red[0][threadIdx.x + s];
            red[1][threadIdx.x] += red[1][threadIdx.x + s];
            red[2][threadIdx.x] += red[2][threadIdx.x + s];
        }
        __syncthreads();
    }
    if (threadIdx.x == 0) {
        double ms = fmax(red[0][0], 1.0);
        out[0] = (float)(red[1][0] / ms + 2.0 * red[2][0] / ms);
    }
}

// ---------------- host launch ----------------

extern "C" void kernel_launch(void* const* d_in, const int* in_sizes, int n_in,
                              void* d_out, int out_size, void* d_ws, size_t ws_size,
                              hipStream_t stream) {
    const float* pred   = (const float*)d_in[0];
    const float* target = (const float*)d_in[1];
    float* out = (float*)d_out;

    const int H = 1024, W = 1024;  // fixed problem shape (W==1024 required by k1)
    int Bn = in_sizes[0] / (3 * H * W);
    size_t plane = (size_t)Bn * H * W * sizeof(float);

    char* ws = (char*)d_ws;
    float* planeA = (float*)ws;            // edge, then mask0 (in place)
    float* planeB = (float*)(ws + plane);  // dilated
    float* partials = (float*)(ws + 2 * plane);

    int g1 = Bn * (H / K1_NR);                 // 1024
    int rs = H / SROWS;                        // 16
    int cbP = (W + 245) / 246;                 // 5
    int cb4 = (W + 251) / 252;                 // 5
    int gP = Bn * cbP * rs;
    int g4 = Bn * cb4 * rs;

    // 1. sobel edge_soft -> planeA
    k1_edge<<<g1, 256, 0, stream>>>(target, planeA, H, W);
    // 2. 11x11 max-pool -> planeB (dilated)
    pool_kernel<5, true, false><<<gP, 256, 0, stream>>>(planeA, nullptr, planeB, H, W);
    // 3. 11x11 min-pool + relu(closed - edge) -> planeA in place (mask0)
    pool_kernel<5, false, true><<<gP, 256, 0, stream>>>(planeB, planeA, planeA, H, W);
    // 4. 5x5 max-pool + compacted masked loss -> partials
    k4_loss<<<g4, 256, 0, stream>>>(pred, target, planeA, partials, H, W, g4);
    // 5. final reduce + combine
    finalize_kernel<<<1, 256, 0, stream>>>(partials, g4, out);
}